// Round 22
// baseline (244.399 us; speedup 1.0000x reference)
//
#include <hip/hip_runtime.h>
#include <math.h>

#define B_ 4
#define C_ 200
#define CH_ 100          // rows per batch half; block r-pair = (c0, c0+100)
#define W_ 300
#define WP_ 304
#define H_ 128
#define NH_ 8
#define PH_ 16
#define FF_ 512
#define L_ 2
#define MAXLEN_ 200
#define PEN_ 512
#define WVS_ 136         // LDS B-matrix row stride (bf16)
#define NTILE_ 19        // ceil(W/16)

typedef __bf16 bf16x8 __attribute__((ext_vector_type(8)));
typedef float f32x4v __attribute__((ext_vector_type(4)));

// prep grid segments
#define SEG_PEW   512
#define SEG_KV    (SEG_PEW + B_ * W_)        // 1712
#define SEG_WR    (SEG_KV + 256)             // 1968
#define SEG_W1T   (SEG_WR + 128)             // 2096
#define SEG_W2T   (SEG_W1T + 128)            // 2224
#define PREP_BLOCKS (SEG_W2T + 32)           // 2256 (WqT: 2l x 4x4 tiles)

// ---------------- prep: PEW | kv | WrB copy | W1T/W2T/WqT LDS-tiled transposes
__global__ __launch_bounds__(128) void prep_kernel(
        const float* __restrict__ Wf, const float* __restrict__ bfv,
        const float* __restrict__ words,
        const float* __restrict__ Wk, const float* __restrict__ bk,
        const float* __restrict__ Wv, const float* __restrict__ bv,
        const float* __restrict__ Wr, const float* __restrict__ W1,
        const float* __restrict__ W2, const float* __restrict__ Wq,
        __bf16* __restrict__ kb, __bf16* __restrict__ PEWb, __bf16* __restrict__ vTb,
        __bf16* __restrict__ WrB, __bf16* __restrict__ W1T, __bf16* __restrict__ W2T,
        __bf16* __restrict__ WqT) {
    __shared__ __align__(16) float s_row[H_];
    __shared__ float s_tile[32][33];
    int t = threadIdx.x;
    if (blockIdx.x < SEG_PEW) {
        int p = blockIdx.x;
        {
            int j = (t < 64) ? t : (t - 64);
            double f = exp(-(double)j * (log(10000.0) / 63.0));
            double a = (double)p * f;
            s_row[t] = (float)((t < 64) ? sin(a) : cos(a));
        }
        __syncthreads();
        float acc0 = 0.f, acc1 = 0.f, acc2 = 0.f, acc3 = 0.f;
        for (int j = 0; j < H_; ++j) {
            float xv = s_row[j];
            int row = j * H_ + t;
            acc0 += xv * Wf[0 * H_ * H_ + row];
            acc1 += xv * Wf[1 * H_ * H_ + row];
            acc2 += xv * Wf[2 * H_ * H_ + row];
            acc3 += xv * Wf[3 * H_ * H_ + row];
        }
        PEWb[(0 * PEN_ + p) * H_ + t] = (__bf16)(acc0 + bfv[t]);
        PEWb[(1 * PEN_ + p) * H_ + t] = (__bf16)acc1;
        PEWb[(2 * PEN_ + p) * H_ + t] = (__bf16)acc2;
        PEWb[(3 * PEN_ + p) * H_ + t] = (__bf16)acc3;
    } else if (blockIdx.x < SEG_KV) {
        int rem = blockIdx.x - SEG_PEW;
        int bb = rem / W_, w = rem % W_;
        s_row[t] = words[rem * H_ + t];
        __syncthreads();
        const float4* row4 = (const float4*)s_row;
        #pragma unroll 1
        for (int li = 0; li < L_; ++li) {
            const float* wk = Wk + li * H_ * H_;
            const float* wv = Wv + li * H_ * H_;
            float4 ak = {0,0,0,0}, av = {0,0,0,0};
            #pragma unroll 2
            for (int g = 0; g < 32; ++g) {
                float4 x = row4[g];
                int j0 = 4 * g;
                ak.x += x.x * wk[(j0 + 0) * H_ + t];
                ak.y += x.y * wk[(j0 + 1) * H_ + t];
                ak.z += x.z * wk[(j0 + 2) * H_ + t];
                ak.w += x.w * wk[(j0 + 3) * H_ + t];
                av.x += x.x * wv[(j0 + 0) * H_ + t];
                av.y += x.y * wv[(j0 + 1) * H_ + t];
                av.z += x.z * wv[(j0 + 2) * H_ + t];
                av.w += x.w * wv[(j0 + 3) * H_ + t];
            }
            kb[(size_t)(li * B_ * W_ + rem) * H_ + t] =
                (__bf16)((ak.x + ak.y) + (ak.z + ak.w) + bk[li * H_ + t]);
            size_t vrow = ((size_t)(li * B_ + bb) * H_ + t) * WP_;
            vTb[vrow + w] = (__bf16)((av.x + av.y) + (av.z + av.w) + bv[li * H_ + t]);
            if (w == 0) {
                vTb[vrow + 300] = (__bf16)0.f; vTb[vrow + 301] = (__bf16)0.f;
                vTb[vrow + 302] = (__bf16)0.f; vTb[vrow + 303] = (__bf16)0.f;
            }
        }
    } else if (blockIdx.x < SEG_WR) {
        int i = (blockIdx.x - SEG_KV) * 128 + t;
        WrB[i] = (__bf16)Wr[i];
    } else if (blockIdx.x < SEG_W1T) {
        int blk = blockIdx.x - SEG_WR;
        int l = blk >> 6;
        int rem = blk & 63;
        int jt = rem >> 4;
        int ut = rem & 15;
        int r = t >> 5, cc = t & 31;
        #pragma unroll
        for (int k = 0; k < 8; ++k) {
            int j = jt * 32 + r + 4 * k;
            s_tile[r + 4 * k][cc] = W1[(l * H_ + j) * FF_ + ut * 32 + cc];
        }
        __syncthreads();
        int jl = t & 31, ul = t >> 5;
        #pragma unroll
        for (int k = 0; k < 8; ++k) {
            int u = ut * 32 + ul + 4 * k;
            W1T[((size_t)(l * FF_ + u)) * H_ + jt * 32 + jl] = (__bf16)s_tile[jl][ul + 4 * k];
        }
    } else if (blockIdx.x < SEG_W2T) {
        int blk = blockIdx.x - SEG_W1T;
        int l = blk >> 6;
        int rem = blk & 63;
        int ut = rem >> 2;
        int ht = rem & 3;
        int r = t >> 5, cc = t & 31;
        #pragma unroll
        for (int k = 0; k < 8; ++k) {
            int u = ut * 32 + r + 4 * k;
            s_tile[r + 4 * k][cc] = W2[(l * FF_ + u) * H_ + ht * 32 + cc];
        }
        __syncthreads();
        int ul = t & 31, hl = t >> 5;
        #pragma unroll
        for (int k = 0; k < 8; ++k) {
            int h = ht * 32 + hl + 4 * k;
            W2T[((size_t)(l * H_ + h)) * FF_ + ut * 32 + ul] = (__bf16)s_tile[ul][hl + 4 * k];
        }
    } else {
        // WqT[l][h][j] = Wq[l][j][h]; 32x32 LDS tiles (2l x 4 jt x 4 ht = 32 blocks)
        int blk = blockIdx.x - SEG_W2T;              // 0..31
        int l = blk >> 4;
        int rem = blk & 15;
        int jt = rem >> 2;
        int ht = rem & 3;
        int r = t >> 5, cc = t & 31;
        #pragma unroll
        for (int k = 0; k < 8; ++k) {
            int j = jt * 32 + r + 4 * k;
            s_tile[r + 4 * k][cc] = Wq[(l * H_ + j) * H_ + ht * 32 + cc];
        }
        __syncthreads();
        int jl = t & 31, hl = t >> 5;
        #pragma unroll
        for (int k = 0; k < 8; ++k) {
            int h = ht * 32 + hl + 4 * k;
            WqT[((size_t)(l * H_ + h)) * H_ + jt * 32 + jl] = (__bf16)s_tile[jl][hl + 4 * k];
        }
    }
}

// ---------------- mega: one block per TWO rows (b,c0) and (b,c0+100); fp32 in/out
// R21 structure (row pairing + layer-invariant rel register cache) + bf16-row qproj
// (one barrier fewer, 64 strided fp32 loads -> 16 contiguous bf16x8 per thread).
__global__ __launch_bounds__(256, 2) void mega_kernel(
    const float* __restrict__ chars,
    const int* __restrict__ pos_s, const int* __restrict__ pos_e,
    const int* __restrict__ lex_s, const int* __restrict__ lex_e,
    const int* __restrict__ seq_len, const int* __restrict__ lex_num,
    const float* __restrict__ bq, const float* __restrict__ br,
    const float* __restrict__ u_bias, const float* __restrict__ v_bias,
    const float* __restrict__ ln1_g, const float* __restrict__ ln1_b,
    const float* __restrict__ ln2_g, const float* __restrict__ ln2_b,
    const float* __restrict__ b1, const float* __restrict__ b2,
    const __bf16* __restrict__ kb, const __bf16* __restrict__ PEWb,
    const __bf16* __restrict__ vTb, const __bf16* __restrict__ WrB,
    const __bf16* __restrict__ W1T, const __bf16* __restrict__ W2T,
    const __bf16* __restrict__ WqT,
    float* __restrict__ out) {

    __shared__ __align__(16) float s_x[2][H_], s_qv[2][H_];
    __shared__ __align__(16) __bf16 s_wvecb[2][16][WVS_];
    __shared__ __align__(16) __bf16 s_qub[2][16][WVS_];
    __shared__ float s_bterm[2][NH_];
    __shared__ __align__(16) float s_sc[2][NH_][WP_];
    __shared__ float s_red[2][132];
    __shared__ __align__(16) float s_hid[2][FF_];
    __shared__ float s_tmp[2][256];
    __shared__ int s_ls[W_], s_le[W_];

    int blk = blockIdx.x;
    int b = blk / CH_, c0 = blk % CH_;
    int t = threadIdx.x;
    int lane = t & 63;
    int wid = t >> 6;
    int l15 = lane & 15, quad = lane >> 4;

    if (t < H_) {
        s_x[0][t] = chars[(b * C_ + c0) * H_ + t];
        s_x[1][t] = chars[(b * C_ + c0 + CH_) * H_ + t];
    }
    for (int w = t; w < W_; w += 256) {
        s_ls[w] = lex_s[b * W_ + w];
        s_le[w] = lex_e[b * W_ + w];
    }
    for (int i = t; i < 2 * 8 * WVS_; i += 256) {
        int r = i / (8 * WVS_), rem = i % (8 * WVS_);
        s_wvecb[r][8 + rem / WVS_][rem % WVS_] = (__bf16)0.f;
    }
    for (int i = t; i < 2 * 16 * WVS_; i += 256) {
        int r = i / (16 * WVS_), rem = i % (16 * WVS_);
        s_qub[r][rem / WVS_][rem % WVS_] = (__bf16)0.f;
    }
    int ps0 = pos_s[b * C_ + c0],        pev0 = pos_e[b * C_ + c0];
    int ps1 = pos_s[b * C_ + c0 + CH_],  pev1 = pos_e[b * C_ + c0 + CH_];
    int slen = seq_len[b];
    int cvalid0 = (c0 < slen), cvalid1 = (c0 + CH_ < slen);
    int wnum = lex_num[b];
    __syncthreads();

    // layer-invariant rel A-fragment cache (built li=0, reused li=1)
    bf16x8 Ac0[5][4], Ac1[5][4];

    #pragma unroll
    for (int li = 0; li < L_; ++li) {
        // ---- q projection: bf16 full-row dots; t<128 -> row0, t>=128 -> row1
        {
            int r = t >> 7, h = t & 127;
            const __bf16* row = WqT + ((size_t)(li * H_ + h)) * H_;
            const float4* x4 = (const float4*)s_x[r];
            float4 a4 = {0,0,0,0};
            #pragma unroll 2
            for (int g = 0; g < 16; ++g) {
                bf16x8 wv = *(const bf16x8*)(row + 8 * g);
                float4 x0 = x4[2 * g], x1 = x4[2 * g + 1];
                a4.x += x0.x * (float)wv[0] + x1.x * (float)wv[4];
                a4.y += x0.y * (float)wv[1] + x1.y * (float)wv[5];
                a4.z += x0.z * (float)wv[2] + x1.z * (float)wv[6];
                a4.w += x0.w * (float)wv[3] + x1.w * (float)wv[7];
            }
            float acc = (a4.x + a4.y) + (a4.z + a4.w) + bq[li * H_ + h];
            s_qub[r][h >> 4][h] = (__bf16)(acc + u_bias[li * H_ + h]);
            s_qv[r][h] = acc + v_bias[li * H_ + h];
        }
        __syncthreads();

        // ---- wvec + bterm
        if (t < H_) {
            const __bf16* WrRow = WrB + li * H_ * H_ + t * H_;
            #pragma unroll 2
            for (int n = 0; n < NH_; ++n) {
                bf16x8 w0 = *(const bf16x8*)(WrRow + n * PH_);
                bf16x8 w1 = *(const bf16x8*)(WrRow + n * PH_ + 8);
                #pragma unroll
                for (int r = 0; r < 2; ++r) {
                    const float4* qv4 = (const float4*)(s_qv[r] + n * PH_);
                    float4 q0 = qv4[0], q1 = qv4[1], q2 = qv4[2], q3 = qv4[3];
                    float4 a4;
                    a4.x = (float)w0[0] * q0.x + (float)w1[0] * q2.x;
                    a4.y = (float)w0[1] * q0.y + (float)w1[1] * q2.y;
                    a4.z = (float)w0[2] * q0.z + (float)w1[2] * q2.z;
                    a4.w = (float)w0[3] * q0.w + (float)w1[3] * q2.w;
                    a4.x += (float)w0[4] * q1.x + (float)w1[4] * q3.x;
                    a4.y += (float)w0[5] * q1.y + (float)w1[5] * q3.y;
                    a4.z += (float)w0[6] * q1.z + (float)w1[6] * q3.z;
                    a4.w += (float)w0[7] * q1.w + (float)w1[7] * q3.w;
                    s_wvecb[r][n][t] = (__bf16)((a4.x + a4.y) + (a4.z + a4.w));
                }
            }
        } else if (t < H_ + NH_) {
            int n = t - H_;
            const float4* br4 = (const float4*)(br + li * H_ + n * PH_);
            float4 b0 = br4[0], b1v = br4[1], b2v = br4[2], b3v = br4[3];
            #pragma unroll
            for (int r = 0; r < 2; ++r) {
                const float4* qv4 = (const float4*)(s_qv[r] + n * PH_);
                float4 q0 = qv4[0], q1 = qv4[1], q2 = qv4[2], q3 = qv4[3];
                float4 a4;
                a4.x = b0.x * q0.x + b2v.x * q2.x;
                a4.y = b0.y * q0.y + b2v.y * q2.y;
                a4.z = b0.z * q0.z + b2v.z * q2.z;
                a4.w = b0.w * q0.w + b2v.w * q2.w;
                a4.x += b1v.x * q1.x + b3v.x * q3.x;
                a4.y += b1v.y * q1.y + b3v.y * q3.y;
                a4.z += b1v.z * q1.z + b3v.z * q3.z;
                a4.w += b1v.w * q1.w + b3v.w * q3.w;
                s_bterm[r][n] = (a4.x + a4.y) + (a4.z + a4.w);
            }
        }
        __syncthreads();

        // ---- score via MFMA; rel A-fragments gathered only in layer 0
        const __bf16* kL = kb + (size_t)(li * B_ + b) * W_ * H_;
        {
            const __bf16* wrow0 = &s_wvecb[0][l15][0];
            const __bf16* wrow1 = &s_wvecb[1][l15][0];
            const __bf16* qrow0 = &s_qub[0][l15][0];
            const __bf16* qrow1 = &s_qub[1][l15][0];
            #pragma unroll
            for (int tc = 0; tc < 5; ++tc) {
                int tile = wid + 4 * tc;
                if (tile < NTILE_) {
                    int w0t = tile * 16;
                    int w = w0t + l15; if (w > W_ - 1) w = W_ - 1;
                    const __bf16* kr = kL + (size_t)w * H_;
                    f32x4v acc0 = {0.f,0.f,0.f,0.f}, acc1 = {0.f,0.f,0.f,0.f};
                    if (li == 0) {
                        int ls = s_ls[w], le = s_le[w];
                        int i00 = min(max(ps0 - ls + MAXLEN_, 0), PEN_ - 1);
                        int i01 = min(max(ps0 - le + MAXLEN_, 0), PEN_ - 1);
                        int i02 = min(max(pev0 - ls + MAXLEN_, 0), PEN_ - 1);
                        int i03 = min(max(pev0 - le + MAXLEN_, 0), PEN_ - 1);
                        int i10 = min(max(ps1 - ls + MAXLEN_, 0), PEN_ - 1);
                        int i11 = min(max(ps1 - le + MAXLEN_, 0), PEN_ - 1);
                        int i12 = min(max(pev1 - ls + MAXLEN_, 0), PEN_ - 1);
                        int i13 = min(max(pev1 - le + MAXLEN_, 0), PEN_ - 1);
                        const __bf16* r00 = PEWb + (size_t)(0 * PEN_ + i00) * H_;
                        const __bf16* r01 = PEWb + (size_t)(1 * PEN_ + i01) * H_;
                        const __bf16* r02 = PEWb + (size_t)(2 * PEN_ + i02) * H_;
                        const __bf16* r03 = PEWb + (size_t)(3 * PEN_ + i03) * H_;
                        const __bf16* r10 = PEWb + (size_t)(0 * PEN_ + i10) * H_;
                        const __bf16* r11 = PEWb + (size_t)(1 * PEN_ + i11) * H_;
                        const __bf16* r12 = PEWb + (size_t)(2 * PEN_ + i12) * H_;
                        const __bf16* r13 = PEWb + (size_t)(3 * PEN_ + i13) * H_;
                        #pragma unroll
                        for (int s = 0; s < 4; ++s) {
                            int h0 = s * 32 + quad * 8;
                            bf16x8 K = *(const bf16x8*)(kr + h0);
                            bf16x8 A0, A1;
                            {
                                bf16x8 t0 = *(const bf16x8*)(r00 + h0);
                                bf16x8 t1 = *(const bf16x8*)(r01 + h0);
                                bf16x8 t2 = *(const bf16x8*)(r02 + h0);
                                bf16x8 t3 = *(const bf16x8*)(r03 + h0);
                                #pragma unroll
                                for (int j = 0; j < 8; ++j)
                                    A0[j] = (__bf16)fmaxf((float)t0[j] + (float)t1[j] + (float)t2[j] + (float)t3[j], 0.f);
                            }
                            {
                                bf16x8 t0 = *(const bf16x8*)(r10 + h0);
                                bf16x8 t1 = *(const bf16x8*)(r11 + h0);
                                bf16x8 t2 = *(const bf16x8*)(r12 + h0);
                                bf16x8 t3 = *(const bf16x8*)(r13 + h0);
                                #pragma unroll
                                for (int j = 0; j < 8; ++j)
                                    A1[j] = (__bf16)fmaxf((float)t0[j] + (float)t1[j] + (float)t2[j] + (float)t3[j], 0.f);
                            }
                            Ac0[tc][s] = A0;
                            Ac1[tc][s] = A1;
                            bf16x8 Bf0 = *(const bf16x8*)(wrow0 + h0);
                            acc0 = __builtin_amdgcn_mfma_f32_16x16x32_bf16(A0, Bf0, acc0, 0, 0, 0);
                            bf16x8 Bq0 = *(const bf16x8*)(qrow0 + h0);
                            acc0 = __builtin_amdgcn_mfma_f32_16x16x32_bf16(K, Bq0, acc0, 0, 0, 0);
                            bf16x8 Bf1 = *(const bf16x8*)(wrow1 + h0);
                            acc1 = __builtin_amdgcn_mfma_f32_16x16x32_bf16(A1, Bf1, acc1, 0, 0, 0);
                            bf16x8 Bq1 = *(const bf16x8*)(qrow1 + h0);
                            acc1 = __builtin_amdgcn_mfma_f32_16x16x32_bf16(K, Bq1, acc1, 0, 0, 0);
                        }
                    } else {
                        #pragma unroll
                        for (int s = 0; s < 4; ++s) {
                            int h0 = s * 32 + quad * 8;
                            bf16x8 K = *(const bf16x8*)(kr + h0);
                            bf16x8 A0 = Ac0[tc][s];
                            bf16x8 A1 = Ac1[tc][s];
                            bf16x8 Bf0 = *(const bf16x8*)(wrow0 + h0);
                            acc0 = __builtin_amdgcn_mfma_f32_16x16x32_bf16(A0, Bf0, acc0, 0, 0, 0);
                            bf16x8 Bq0 = *(const bf16x8*)(qrow0 + h0);
                            acc0 = __builtin_amdgcn_mfma_f32_16x16x32_bf16(K, Bq0, acc0, 0, 0, 0);
                            bf16x8 Bf1 = *(const bf16x8*)(wrow1 + h0);
                            acc1 = __builtin_amdgcn_mfma_f32_16x16x32_bf16(A1, Bf1, acc1, 0, 0, 0);
                            bf16x8 Bq1 = *(const bf16x8*)(qrow1 + h0);
                            acc1 = __builtin_amdgcn_mfma_f32_16x16x32_bf16(K, Bq1, acc1, 0, 0, 0);
                        }
                    }
                    if (l15 < NH_) {
                        float bt0 = s_bterm[0][l15], bt1 = s_bterm[1][l15];
                        #pragma unroll
                        for (int r = 0; r < 4; ++r) {
                            int wr = w0t + quad * 4 + r;
                            if (wr < W_) {
                                s_sc[0][l15][wr] = acc0[r] + bt0;
                                s_sc[1][l15][wr] = acc1[r] + bt1;
                            }
                        }
                    }
                }
            }
        }
        __syncthreads();

        // ---- softmax per head, per row
        {
            int n = t >> 5, ln_ = t & 31;
            #pragma unroll
            for (int r = 0; r < 2; ++r) {
                int cval = r ? cvalid1 : cvalid0;
                if (cval) {
                    float m = -INFINITY;
                    for (int w = ln_; w < wnum; w += 32) m = fmaxf(m, s_sc[r][n][w]);
                    #pragma unroll
                    for (int off = 16; off > 0; off >>= 1) m = fmaxf(m, __shfl_xor(m, off, 32));
                    float sum = 0.f;
                    for (int w = ln_; w < wnum; w += 32) sum += expf(s_sc[r][n][w] - m);
                    #pragma unroll
                    for (int off = 16; off > 0; off >>= 1) sum += __shfl_xor(sum, off, 32);
                    float inv = 1.f / sum;
                    for (int w = ln_; w < WP_; w += 32)
                        s_sc[r][n][w] = (w < wnum) ? expf(s_sc[r][n][w] - m) * inv : 0.f;
                } else {
                    for (int w = ln_; w < WP_; w += 32) s_sc[r][n][w] = 0.f;
                }
            }
        }
        __syncthreads();

        // ---- ctx = att @ v
        {
            int h = t & 127, half = t >> 7, n = h >> 4;
            const __bf16* vrow = vTb + ((size_t)(li * B_ + b) * H_ + h) * WP_;
            const float4* att0 = (const float4*)(s_sc[0][n]);
            const float4* att1 = (const float4*)(s_sc[1][n]);
            float4 a0 = {0,0,0,0}, a1 = {0,0,0,0};
            #pragma unroll 2
            for (int g = half * 19; g < half * 19 + 19; ++g) {
                bf16x8 vv = *(const bf16x8*)(vrow + 8 * g);
                float4 p00 = att0[2 * g], p01 = att0[2 * g + 1];
                float4 p10 = att1[2 * g], p11 = att1[2 * g + 1];
                float v0 = (float)vv[0], v1 = (float)vv[1], v2 = (float)vv[2], v3 = (float)vv[3];
                float v4 = (float)vv[4], v5 = (float)vv[5], v6 = (float)vv[6], v7 = (float)vv[7];
                a0.x += p00.x * v0 + p01.x * v4;
                a0.y += p00.y * v1 + p01.y * v5;
                a0.z += p00.z * v2 + p01.z * v6;
                a0.w += p00.w * v3 + p01.w * v7;
                a1.x += p10.x * v0 + p11.x * v4;
                a1.y += p10.y * v1 + p11.y * v5;
                a1.z += p10.z * v2 + p11.z * v6;
                a1.w += p10.w * v3 + p11.w * v7;
            }
            s_tmp[0][t] = (a0.x + a0.y) + (a0.z + a0.w);
            s_tmp[1][t] = (a1.x + a1.y) + (a1.z + a1.w);
        }
        __syncthreads();

        // ---- LN1
        if (t < 128) {
            s_red[0][t] = s_tmp[0][t] + s_tmp[0][t + 128] + s_x[0][t];
        } else {
            int e = t - 128;
            s_red[1][e] = s_tmp[1][e] + s_tmp[1][e + 128] + s_x[1][e];
        }
        __syncthreads();
        if (t < 128) {
            int r = t >> 6, l = t & 63;
            float a = s_red[r][l], bb = s_red[r][l + 64];
            float s = a + bb, ss = a * a + bb * bb;
            #pragma unroll
            for (int off = 32; off > 0; off >>= 1) {
                s += __shfl_down(s, off);
                ss += __shfl_down(ss, off);
            }
            if (l == 0) {
                float mean = s * (1.f / 128.f);
                float var = ss * (1.f / 128.f) - mean * mean;
                s_red[r][128] = mean;
                s_red[r][129] = rsqrtf(var + 1e-5f);
            }
        }
        __syncthreads();
        if (t < H_) {
            float g1 = ln1_g[li * H_ + t], b1v = ln1_b[li * H_ + t];
            #pragma unroll
            for (int r = 0; r < 2; ++r)
                s_x[r][t] = (s_red[r][t] - s_red[r][128]) * s_red[r][129] * g1 + b1v;
        }
        __syncthreads();

        // ---- FF hidden
        {
            const __bf16* W1l = W1T + (size_t)li * FF_ * H_;
            int u0 = t * 2;
            const __bf16* ra = W1l + (size_t)u0 * H_;
            const __bf16* rb = W1l + (size_t)(u0 + 1) * H_;
            const float4* x40 = (const float4*)s_x[0];
            const float4* x41 = (const float4*)s_x[1];
            float4 a00 = {0,0,0,0}, a01 = {0,0,0,0}, a10 = {0,0,0,0}, a11 = {0,0,0,0};
            #pragma unroll 2
            for (int g = 0; g < 16; ++g) {
                bf16x8 wa = *(const bf16x8*)(ra + 8 * g);
                bf16x8 wb = *(const bf16x8*)(rb + 8 * g);
                float4 xa0 = x40[2 * g], xa1 = x40[2 * g + 1];
                float4 xb0 = x41[2 * g], xb1 = x41[2 * g + 1];
                a00.x += xa0.x * (float)wa[0] + xa1.x * (float)wa[4];
                a00.y += xa0.y * (float)wa[1] + xa1.y * (float)wa[5];
                a00.z += xa0.z * (float)wa[2] + xa1.z * (float)wa[6];
                a00.w += xa0.w * (float)wa[3] + xa1.w * (float)wa[7];
                a01.x += xa0.x * (float)wb[0] + xa1.x * (float)wb[4];
                a01.y += xa0.y * (float)wb[1] + xa1.y * (float)wb[5];
                a01.z += xa0.z * (float)wb[2] + xa1.z * (float)wb[6];
                a01.w += xa0.w * (float)wb[3] + xa1.w * (float)wb[7];
                a10.x += xb0.x * (float)wa[0] + xb1.x * (float)wa[4];
                a10.y += xb0.y * (float)wa[1] + xb1.y * (float)wa[5];
                a10.z += xb0.z * (float)wa[2] + xb1.z * (float)wa[6];
                a10.w += xb0.w * (float)wa[3] + xb1.w * (float)wa[7];
                a11.x += xb0.x * (float)wb[0] + xb1.x * (float)wb[4];
                a11.y += xb0.y * (float)wb[1] + xb1.y * (float)wb[5];
                a11.z += xb0.z * (float)wb[2] + xb1.z * (float)wb[6];
                a11.w += xb0.w * (float)wb[3] + xb1.w * (float)wb[7];
            }
            float bb0 = b1[li * FF_ + u0], bb1 = b1[li * FF_ + u0 + 1];
            s_hid[0][u0]     = fmaxf((a00.x + a00.y) + (a00.z + a00.w) + bb0, 0.f);
            s_hid[0][u0 + 1] = fmaxf((a01.x + a01.y) + (a01.z + a01.w) + bb1, 0.f);
            s_hid[1][u0]     = fmaxf((a10.x + a10.y) + (a10.z + a10.w) + bb0, 0.f);
            s_hid[1][u0 + 1] = fmaxf((a11.x + a11.y) + (a11.z + a11.w) + bb1, 0.f);
        }
        __syncthreads();

        // ---- FF out
        {
            int half = t >> 7, h = t & 127;
            const __bf16* wrow2 = W2T + ((size_t)li * H_ + h) * FF_ + half * 256;
            const float4* h40 = (const float4*)(s_hid[0] + half * 256);
            const float4* h41 = (const float4*)(s_hid[1] + half * 256);
            float4 a0 = {0,0,0,0}, a1 = {0,0,0,0};
            #pragma unroll 2
            for (int g = 0; g < 32; ++g) {
                bf16x8 wv = *(const bf16x8*)(wrow2 + 8 * g);
                float4 p00 = h40[2 * g], p01 = h40[2 * g + 1];
                float4 p10 = h41[2 * g], p11 = h41[2 * g + 1];
                float v0 = (float)wv[0], v1 = (float)wv[1], v2 = (float)wv[2], v3 = (float)wv[3];
                float v4 = (float)wv[4], v5 = (float)wv[5], v6 = (float)wv[6], v7 = (float)wv[7];
                a0.x += p00.x * v0 + p01.x * v4;
                a0.y += p00.y * v1 + p01.y * v5;
                a0.z += p00.z * v2 + p01.z * v6;
                a0.w += p00.w * v3 + p01.w * v7;
                a1.x += p10.x * v0 + p11.x * v4;
                a1.y += p10.y * v1 + p11.y * v5;
                a1.z += p10.z * v2 + p11.z * v6;
                a1.w += p10.w * v3 + p11.w * v7;
            }
            s_tmp[0][t] = (a0.x + a0.y) + (a0.z + a0.w);
            s_tmp[1][t] = (a1.x + a1.y) + (a1.z + a1.w);
        }
        __syncthreads();

        // ---- LN2
        if (t < 128) {
            s_red[0][t] = s_tmp[0][t] + s_tmp[0][t + 128] + b2[li * H_ + t] + s_x[0][t];
        } else {
            int e = t - 128;
            s_red[1][e] = s_tmp[1][e] + s_tmp[1][e + 128] + b2[li * H_ + e] + s_x[1][e];
        }
        __syncthreads();
        if (t < 128) {
            int r = t >> 6, l = t & 63;
            float a = s_red[r][l], bb = s_red[r][l + 64];
            float s = a + bb, ss = a * a + bb * bb;
            #pragma unroll
            for (int off = 32; off > 0; off >>= 1) {
                s += __shfl_down(s, off);
                ss += __shfl_down(ss, off);
            }
            if (l == 0) {
                float mean = s * (1.f / 128.f);
                float var = ss * (1.f / 128.f) - mean * mean;
                s_red[r][128] = mean;
                s_red[r][129] = rsqrtf(var + 1e-5f);
            }
        }
        __syncthreads();
        if (t < H_) {
            float g2 = ln2_g[li * H_ + t], b2v = ln2_b[li * H_ + t];
            #pragma unroll
            for (int r = 0; r < 2; ++r)
                s_x[r][t] = (s_red[r][t] - s_red[r][128]) * s_red[r][129] * g2 + b2v;
        }
        __syncthreads();
    }

    if (t < H_) {
        out[(b * C_ + c0) * H_ + t] = s_x[0][t];
        out[(b * C_ + c0 + CH_) * H_ + t] = s_x[1][t];
    }
}

extern "C" void kernel_launch(void* const* d_in, const int* in_sizes, int n_in,
                              void* d_out, int out_size, void* d_ws, size_t ws_size,
                              hipStream_t stream) {
    const float* chars  = (const float*)d_in[0];
    const float* words  = (const float*)d_in[1];
    const int* pos_s   = (const int*)d_in[2];
    const int* pos_e   = (const int*)d_in[3];
    const int* lex_s   = (const int*)d_in[4];
    const int* lex_e   = (const int*)d_in[5];
    const int* seq_len = (const int*)d_in[6];
    const int* lex_num = (const int*)d_in[7];
    const float* Wf  = (const float*)d_in[8];
    const float* bfv = (const float*)d_in[9];
    const float* Wq  = (const float*)d_in[10];
    const float* bq  = (const float*)d_in[11];
    const float* Wk  = (const float*)d_in[12];
    const float* bk  = (const float*)d_in[13];
    const float* Wv  = (const float*)d_in[14];
    const float* bv  = (const float*)d_in[15];
    const float* Wr  = (const float*)d_in[16];
    const float* br  = (const float*)d_in[17];
    const float* u_bias = (const float*)d_in[18];
    const float* v_bias = (const float*)d_in[19];
    const float* ln1_g  = (const float*)d_in[20];
    const float* ln1_b  = (const float*)d_in[21];
    const float* ln2_g  = (const float*)d_in[22];
    const float* ln2_b  = (const float*)d_in[23];
    const float* W1  = (const float*)d_in[24];
    const float* b1  = (const float*)d_in[25];
    const float* W2  = (const float*)d_in[26];
    const float* b2  = (const float*)d_in[27];

    __bf16* kb   = (__bf16*)d_ws;                      // L*B*W*H  = 307200 bf16
    __bf16* PEWb = kb + (size_t)L_ * B_ * W_ * H_;     // 262144 bf16
    __bf16* vTb  = PEWb + 4 * PEN_ * H_;               // L*B*H*WP = 311296 bf16
    __bf16* WrB  = vTb + (size_t)L_ * B_ * H_ * WP_;   // 32768 bf16
    __bf16* W1T  = WrB + L_ * H_ * H_;                 // 131072 bf16
    __bf16* W2T  = W1T + L_ * H_ * FF_;                // 131072 bf16
    __bf16* WqT  = W2T + L_ * H_ * FF_;                // 32768 bf16

    prep_kernel<<<dim3(PREP_BLOCKS), dim3(128), 0, stream>>>(
        Wf, bfv, words, Wk, bk, Wv, bv, Wr, W1, W2, Wq,
        kb, PEWb, vTb, WrB, W1T, W2T, WqT);

    mega_kernel<<<dim3(B_ * CH_), dim3(256), 0, stream>>>(
        chars, pos_s, pos_e, lex_s, lex_e, seq_len, lex_num,
        bq, br, u_bias, v_bias,
        ln1_g, ln1_b, ln2_g, ln2_b, b1, b2,
        kb, PEWb, vTb, WrB, W1T, W2T, WqT, (float*)d_out);
}

// Round 23
// 240.102 us; speedup vs baseline: 1.0179x; 1.0179x over previous
//
#include <hip/hip_runtime.h>
#include <math.h>

#define B_ 4
#define C_ 200
#define CH_ 100          // rows per batch half; block r-pair = (c0, c0+100)
#define W_ 300
#define WP_ 304
#define H_ 128
#define NH_ 8
#define PH_ 16
#define FF_ 512
#define L_ 2
#define MAXLEN_ 200
#define PEN_ 512
#define WVS_ 136         // LDS B-matrix row stride (bf16)
#define NTILE_ 19        // ceil(W/16)

typedef __bf16 bf16x8 __attribute__((ext_vector_type(8)));
typedef float f32x4v __attribute__((ext_vector_type(4)));

// prep grid segments (coalesced transposes, layer-merged kv)
#define SEG_PEW   512
#define SEG_KV    (SEG_PEW + B_ * W_)        // 1712
#define SEG_WR    (SEG_KV + 256)             // 1968
#define SEG_W1T   (SEG_WR + 128)             // 2096
#define PREP_BLOCKS (SEG_W1T + 128)          // 2224

// ---------------- prep: PEW | kv(both layers) | WrB copy | LDS-tiled transposes
__global__ __launch_bounds__(128) void prep_kernel(
        const float* __restrict__ Wf, const float* __restrict__ bfv,
        const float* __restrict__ words,
        const float* __restrict__ Wk, const float* __restrict__ bk,
        const float* __restrict__ Wv, const float* __restrict__ bv,
        const float* __restrict__ Wr, const float* __restrict__ W1,
        const float* __restrict__ W2,
        __bf16* __restrict__ kb, __bf16* __restrict__ PEWb, __bf16* __restrict__ vTb,
        __bf16* __restrict__ WrB, __bf16* __restrict__ W1T, __bf16* __restrict__ W2T) {
    __shared__ __align__(16) float s_row[H_];
    __shared__ float s_tile[32][33];
    int t = threadIdx.x;
    if (blockIdx.x < SEG_PEW) {
        int p = blockIdx.x;
        {
            int j = (t < 64) ? t : (t - 64);
            double f = exp(-(double)j * (log(10000.0) / 63.0));
            double a = (double)p * f;
            s_row[t] = (float)((t < 64) ? sin(a) : cos(a));
        }
        __syncthreads();
        float acc0 = 0.f, acc1 = 0.f, acc2 = 0.f, acc3 = 0.f;
        for (int j = 0; j < H_; ++j) {
            float xv = s_row[j];
            int row = j * H_ + t;
            acc0 += xv * Wf[0 * H_ * H_ + row];
            acc1 += xv * Wf[1 * H_ * H_ + row];
            acc2 += xv * Wf[2 * H_ * H_ + row];
            acc3 += xv * Wf[3 * H_ * H_ + row];
        }
        PEWb[(0 * PEN_ + p) * H_ + t] = (__bf16)(acc0 + bfv[t]);
        PEWb[(1 * PEN_ + p) * H_ + t] = (__bf16)acc1;
        PEWb[(2 * PEN_ + p) * H_ + t] = (__bf16)acc2;
        PEWb[(3 * PEN_ + p) * H_ + t] = (__bf16)acc3;
    } else if (blockIdx.x < SEG_KV) {
        int rem = blockIdx.x - SEG_PEW;
        int bb = rem / W_, w = rem % W_;
        s_row[t] = words[rem * H_ + t];
        __syncthreads();
        const float4* row4 = (const float4*)s_row;
        #pragma unroll 1
        for (int li = 0; li < L_; ++li) {
            const float* wk = Wk + li * H_ * H_;
            const float* wv = Wv + li * H_ * H_;
            float4 ak = {0,0,0,0}, av = {0,0,0,0};
            #pragma unroll 2
            for (int g = 0; g < 32; ++g) {
                float4 x = row4[g];
                int j0 = 4 * g;
                ak.x += x.x * wk[(j0 + 0) * H_ + t];
                ak.y += x.y * wk[(j0 + 1) * H_ + t];
                ak.z += x.z * wk[(j0 + 2) * H_ + t];
                ak.w += x.w * wk[(j0 + 3) * H_ + t];
                av.x += x.x * wv[(j0 + 0) * H_ + t];
                av.y += x.y * wv[(j0 + 1) * H_ + t];
                av.z += x.z * wv[(j0 + 2) * H_ + t];
                av.w += x.w * wv[(j0 + 3) * H_ + t];
            }
            kb[(size_t)(li * B_ * W_ + rem) * H_ + t] =
                (__bf16)((ak.x + ak.y) + (ak.z + ak.w) + bk[li * H_ + t]);
            size_t vrow = ((size_t)(li * B_ + bb) * H_ + t) * WP_;
            vTb[vrow + w] = (__bf16)((av.x + av.y) + (av.z + av.w) + bv[li * H_ + t]);
            if (w == 0) {
                vTb[vrow + 300] = (__bf16)0.f; vTb[vrow + 301] = (__bf16)0.f;
                vTb[vrow + 302] = (__bf16)0.f; vTb[vrow + 303] = (__bf16)0.f;
            }
        }
    } else if (blockIdx.x < SEG_WR) {
        int i = (blockIdx.x - SEG_KV) * 128 + t;
        WrB[i] = (__bf16)Wr[i];
    } else if (blockIdx.x < SEG_W1T) {
        int blk = blockIdx.x - SEG_WR;
        int l = blk >> 6;
        int rem = blk & 63;
        int jt = rem >> 4;
        int ut = rem & 15;
        int r = t >> 5, cc = t & 31;
        #pragma unroll
        for (int k = 0; k < 8; ++k) {
            int j = jt * 32 + r + 4 * k;
            s_tile[r + 4 * k][cc] = W1[(l * H_ + j) * FF_ + ut * 32 + cc];
        }
        __syncthreads();
        int jl = t & 31, ul = t >> 5;
        #pragma unroll
        for (int k = 0; k < 8; ++k) {
            int u = ut * 32 + ul + 4 * k;
            W1T[((size_t)(l * FF_ + u)) * H_ + jt * 32 + jl] = (__bf16)s_tile[jl][ul + 4 * k];
        }
    } else {
        int blk = blockIdx.x - SEG_W1T;
        int l = blk >> 6;
        int rem = blk & 63;
        int ut = rem >> 2;
        int ht = rem & 3;
        int r = t >> 5, cc = t & 31;
        #pragma unroll
        for (int k = 0; k < 8; ++k) {
            int u = ut * 32 + r + 4 * k;
            s_tile[r + 4 * k][cc] = W2[(l * FF_ + u) * H_ + ht * 32 + cc];
        }
        __syncthreads();
        int ul = t & 31, hl = t >> 5;
        #pragma unroll
        for (int k = 0; k < 8; ++k) {
            int h = ht * 32 + hl + 4 * k;
            W2T[((size_t)(l * H_ + h)) * FF_ + ut * 32 + ul] = (__bf16)s_tile[ul][hl + 4 * k];
        }
    }
}

// ---------------- mega: one block per TWO rows (b,c0) and (b,c0+100); fp32 in/out
// R21 (best measured): row pairing + layer-invariant rel A-fragment register cache.
__global__ __launch_bounds__(256, 2) void mega_kernel(
    const float* __restrict__ chars,
    const int* __restrict__ pos_s, const int* __restrict__ pos_e,
    const int* __restrict__ lex_s, const int* __restrict__ lex_e,
    const int* __restrict__ seq_len, const int* __restrict__ lex_num,
    const float* __restrict__ Wq, const float* __restrict__ bq,
    const float* __restrict__ br,
    const float* __restrict__ u_bias, const float* __restrict__ v_bias,
    const float* __restrict__ ln1_g, const float* __restrict__ ln1_b,
    const float* __restrict__ ln2_g, const float* __restrict__ ln2_b,
    const float* __restrict__ b1, const float* __restrict__ b2,
    const __bf16* __restrict__ kb, const __bf16* __restrict__ PEWb,
    const __bf16* __restrict__ vTb, const __bf16* __restrict__ WrB,
    const __bf16* __restrict__ W1T, const __bf16* __restrict__ W2T,
    float* __restrict__ out) {

    __shared__ __align__(16) float s_x[2][H_], s_qv[2][H_];
    __shared__ __align__(16) __bf16 s_wvecb[2][16][WVS_];
    __shared__ __align__(16) __bf16 s_qub[2][16][WVS_];
    __shared__ float s_bterm[2][NH_];
    __shared__ __align__(16) float s_sc[2][NH_][WP_];
    __shared__ float s_red[2][132];
    __shared__ __align__(16) float s_hid[2][FF_];
    __shared__ float s_tmp[2][256];
    __shared__ int s_ls[W_], s_le[W_];

    int blk = blockIdx.x;
    int b = blk / CH_, c0 = blk % CH_;
    int t = threadIdx.x;
    int lane = t & 63;
    int wid = t >> 6;
    int l15 = lane & 15, quad = lane >> 4;

    if (t < H_) {
        s_x[0][t] = chars[(b * C_ + c0) * H_ + t];
        s_x[1][t] = chars[(b * C_ + c0 + CH_) * H_ + t];
    }
    for (int w = t; w < W_; w += 256) {
        s_ls[w] = lex_s[b * W_ + w];
        s_le[w] = lex_e[b * W_ + w];
    }
    for (int i = t; i < 2 * 8 * WVS_; i += 256) {
        int r = i / (8 * WVS_), rem = i % (8 * WVS_);
        s_wvecb[r][8 + rem / WVS_][rem % WVS_] = (__bf16)0.f;
    }
    for (int i = t; i < 2 * 16 * WVS_; i += 256) {
        int r = i / (16 * WVS_), rem = i % (16 * WVS_);
        s_qub[r][rem / WVS_][rem % WVS_] = (__bf16)0.f;
    }
    int ps0 = pos_s[b * C_ + c0],        pev0 = pos_e[b * C_ + c0];
    int ps1 = pos_s[b * C_ + c0 + CH_],  pev1 = pos_e[b * C_ + c0 + CH_];
    int slen = seq_len[b];
    int cvalid0 = (c0 < slen), cvalid1 = (c0 + CH_ < slen);
    int wnum = lex_num[b];
    __syncthreads();

    // layer-invariant rel A-fragment cache (built li=0, reused li=1)
    bf16x8 Ac0[5][4], Ac1[5][4];

    #pragma unroll
    for (int li = 0; li < L_; ++li) {
        // ---- q projection
        {
            int half = t >> 7, h = t & 127;
            const float* WqL = Wq + li * H_ * H_;
            const float4* x40 = (const float4*)s_x[0];
            const float4* x41 = (const float4*)s_x[1];
            float4 a0 = {0,0,0,0}, a1 = {0,0,0,0};
            #pragma unroll 2
            for (int g = half * 16; g < half * 16 + 16; ++g) {
                float4 xa = x40[g], xb = x41[g];
                int j0 = 4 * g;
                float w0 = WqL[(j0 + 0) * H_ + h], w1 = WqL[(j0 + 1) * H_ + h];
                float w2 = WqL[(j0 + 2) * H_ + h], w3 = WqL[(j0 + 3) * H_ + h];
                a0.x += xa.x * w0; a0.y += xa.y * w1; a0.z += xa.z * w2; a0.w += xa.w * w3;
                a1.x += xb.x * w0; a1.y += xb.y * w1; a1.z += xb.z * w2; a1.w += xb.w * w3;
            }
            s_tmp[0][t] = (a0.x + a0.y) + (a0.z + a0.w);
            s_tmp[1][t] = (a1.x + a1.y) + (a1.z + a1.w);
        }
        __syncthreads();
        if (t < H_) {
            #pragma unroll
            for (int r = 0; r < 2; ++r) {
                float acc = s_tmp[r][t] + s_tmp[r][t + 128] + bq[li * H_ + t];
                s_qub[r][t >> 4][t] = (__bf16)(acc + u_bias[li * H_ + t]);
                s_qv[r][t] = acc + v_bias[li * H_ + t];
            }
        }
        __syncthreads();

        // ---- wvec + bterm
        if (t < H_) {
            const __bf16* WrRow = WrB + li * H_ * H_ + t * H_;
            #pragma unroll 2
            for (int n = 0; n < NH_; ++n) {
                bf16x8 w0 = *(const bf16x8*)(WrRow + n * PH_);
                bf16x8 w1 = *(const bf16x8*)(WrRow + n * PH_ + 8);
                #pragma unroll
                for (int r = 0; r < 2; ++r) {
                    const float4* qv4 = (const float4*)(s_qv[r] + n * PH_);
                    float4 q0 = qv4[0], q1 = qv4[1], q2 = qv4[2], q3 = qv4[3];
                    float4 a4;
                    a4.x = (float)w0[0] * q0.x + (float)w1[0] * q2.x;
                    a4.y = (float)w0[1] * q0.y + (float)w1[1] * q2.y;
                    a4.z = (float)w0[2] * q0.z + (float)w1[2] * q2.z;
                    a4.w = (float)w0[3] * q0.w + (float)w1[3] * q2.w;
                    a4.x += (float)w0[4] * q1.x + (float)w1[4] * q3.x;
                    a4.y += (float)w0[5] * q1.y + (float)w1[5] * q3.y;
                    a4.z += (float)w0[6] * q1.z + (float)w1[6] * q3.z;
                    a4.w += (float)w0[7] * q1.w + (float)w1[7] * q3.w;
                    s_wvecb[r][n][t] = (__bf16)((a4.x + a4.y) + (a4.z + a4.w));
                }
            }
        } else if (t < H_ + NH_) {
            int n = t - H_;
            const float4* br4 = (const float4*)(br + li * H_ + n * PH_);
            float4 b0 = br4[0], b1v = br4[1], b2v = br4[2], b3v = br4[3];
            #pragma unroll
            for (int r = 0; r < 2; ++r) {
                const float4* qv4 = (const float4*)(s_qv[r] + n * PH_);
                float4 q0 = qv4[0], q1 = qv4[1], q2 = qv4[2], q3 = qv4[3];
                float4 a4;
                a4.x = b0.x * q0.x + b2v.x * q2.x;
                a4.y = b0.y * q0.y + b2v.y * q2.y;
                a4.z = b0.z * q0.z + b2v.z * q2.z;
                a4.w = b0.w * q0.w + b2v.w * q2.w;
                a4.x += b1v.x * q1.x + b3v.x * q3.x;
                a4.y += b1v.y * q1.y + b3v.y * q3.y;
                a4.z += b1v.z * q1.z + b3v.z * q3.z;
                a4.w += b1v.w * q1.w + b3v.w * q3.w;
                s_bterm[r][n] = (a4.x + a4.y) + (a4.z + a4.w);
            }
        }
        __syncthreads();

        // ---- score via MFMA; rel A-fragments gathered only in layer 0
        const __bf16* kL = kb + (size_t)(li * B_ + b) * W_ * H_;
        {
            const __bf16* wrow0 = &s_wvecb[0][l15][0];
            const __bf16* wrow1 = &s_wvecb[1][l15][0];
            const __bf16* qrow0 = &s_qub[0][l15][0];
            const __bf16* qrow1 = &s_qub[1][l15][0];
            #pragma unroll
            for (int tc = 0; tc < 5; ++tc) {
                int tile = wid + 4 * tc;
                if (tile < NTILE_) {
                    int w0t = tile * 16;
                    int w = w0t + l15; if (w > W_ - 1) w = W_ - 1;
                    const __bf16* kr = kL + (size_t)w * H_;
                    f32x4v acc0 = {0.f,0.f,0.f,0.f}, acc1 = {0.f,0.f,0.f,0.f};
                    if (li == 0) {
                        int ls = s_ls[w], le = s_le[w];
                        int i00 = min(max(ps0 - ls + MAXLEN_, 0), PEN_ - 1);
                        int i01 = min(max(ps0 - le + MAXLEN_, 0), PEN_ - 1);
                        int i02 = min(max(pev0 - ls + MAXLEN_, 0), PEN_ - 1);
                        int i03 = min(max(pev0 - le + MAXLEN_, 0), PEN_ - 1);
                        int i10 = min(max(ps1 - ls + MAXLEN_, 0), PEN_ - 1);
                        int i11 = min(max(ps1 - le + MAXLEN_, 0), PEN_ - 1);
                        int i12 = min(max(pev1 - ls + MAXLEN_, 0), PEN_ - 1);
                        int i13 = min(max(pev1 - le + MAXLEN_, 0), PEN_ - 1);
                        const __bf16* r00 = PEWb + (size_t)(0 * PEN_ + i00) * H_;
                        const __bf16* r01 = PEWb + (size_t)(1 * PEN_ + i01) * H_;
                        const __bf16* r02 = PEWb + (size_t)(2 * PEN_ + i02) * H_;
                        const __bf16* r03 = PEWb + (size_t)(3 * PEN_ + i03) * H_;
                        const __bf16* r10 = PEWb + (size_t)(0 * PEN_ + i10) * H_;
                        const __bf16* r11 = PEWb + (size_t)(1 * PEN_ + i11) * H_;
                        const __bf16* r12 = PEWb + (size_t)(2 * PEN_ + i12) * H_;
                        const __bf16* r13 = PEWb + (size_t)(3 * PEN_ + i13) * H_;
                        #pragma unroll
                        for (int s = 0; s < 4; ++s) {
                            int h0 = s * 32 + quad * 8;
                            bf16x8 K = *(const bf16x8*)(kr + h0);
                            bf16x8 A0, A1;
                            {
                                bf16x8 t0 = *(const bf16x8*)(r00 + h0);
                                bf16x8 t1 = *(const bf16x8*)(r01 + h0);
                                bf16x8 t2 = *(const bf16x8*)(r02 + h0);
                                bf16x8 t3 = *(const bf16x8*)(r03 + h0);
                                #pragma unroll
                                for (int j = 0; j < 8; ++j)
                                    A0[j] = (__bf16)fmaxf((float)t0[j] + (float)t1[j] + (float)t2[j] + (float)t3[j], 0.f);
                            }
                            {
                                bf16x8 t0 = *(const bf16x8*)(r10 + h0);
                                bf16x8 t1 = *(const bf16x8*)(r11 + h0);
                                bf16x8 t2 = *(const bf16x8*)(r12 + h0);
                                bf16x8 t3 = *(const bf16x8*)(r13 + h0);
                                #pragma unroll
                                for (int j = 0; j < 8; ++j)
                                    A1[j] = (__bf16)fmaxf((float)t0[j] + (float)t1[j] + (float)t2[j] + (float)t3[j], 0.f);
                            }
                            Ac0[tc][s] = A0;
                            Ac1[tc][s] = A1;
                            bf16x8 Bf0 = *(const bf16x8*)(wrow0 + h0);
                            acc0 = __builtin_amdgcn_mfma_f32_16x16x32_bf16(A0, Bf0, acc0, 0, 0, 0);
                            bf16x8 Bq0 = *(const bf16x8*)(qrow0 + h0);
                            acc0 = __builtin_amdgcn_mfma_f32_16x16x32_bf16(K, Bq0, acc0, 0, 0, 0);
                            bf16x8 Bf1 = *(const bf16x8*)(wrow1 + h0);
                            acc1 = __builtin_amdgcn_mfma_f32_16x16x32_bf16(A1, Bf1, acc1, 0, 0, 0);
                            bf16x8 Bq1 = *(const bf16x8*)(qrow1 + h0);
                            acc1 = __builtin_amdgcn_mfma_f32_16x16x32_bf16(K, Bq1, acc1, 0, 0, 0);
                        }
                    } else {
                        #pragma unroll
                        for (int s = 0; s < 4; ++s) {
                            int h0 = s * 32 + quad * 8;
                            bf16x8 K = *(const bf16x8*)(kr + h0);
                            bf16x8 A0 = Ac0[tc][s];
                            bf16x8 A1 = Ac1[tc][s];
                            bf16x8 Bf0 = *(const bf16x8*)(wrow0 + h0);
                            acc0 = __builtin_amdgcn_mfma_f32_16x16x32_bf16(A0, Bf0, acc0, 0, 0, 0);
                            bf16x8 Bq0 = *(const bf16x8*)(qrow0 + h0);
                            acc0 = __builtin_amdgcn_mfma_f32_16x16x32_bf16(K, Bq0, acc0, 0, 0, 0);
                            bf16x8 Bf1 = *(const bf16x8*)(wrow1 + h0);
                            acc1 = __builtin_amdgcn_mfma_f32_16x16x32_bf16(A1, Bf1, acc1, 0, 0, 0);
                            bf16x8 Bq1 = *(const bf16x8*)(qrow1 + h0);
                            acc1 = __builtin_amdgcn_mfma_f32_16x16x32_bf16(K, Bq1, acc1, 0, 0, 0);
                        }
                    }
                    if (l15 < NH_) {
                        float bt0 = s_bterm[0][l15], bt1 = s_bterm[1][l15];
                        #pragma unroll
                        for (int r = 0; r < 4; ++r) {
                            int wr = w0t + quad * 4 + r;
                            if (wr < W_) {
                                s_sc[0][l15][wr] = acc0[r] + bt0;
                                s_sc[1][l15][wr] = acc1[r] + bt1;
                            }
                        }
                    }
                }
            }
        }
        __syncthreads();

        // ---- softmax per head, per row
        {
            int n = t >> 5, ln_ = t & 31;
            #pragma unroll
            for (int r = 0; r < 2; ++r) {
                int cval = r ? cvalid1 : cvalid0;
                if (cval) {
                    float m = -INFINITY;
                    for (int w = ln_; w < wnum; w += 32) m = fmaxf(m, s_sc[r][n][w]);
                    #pragma unroll
                    for (int off = 16; off > 0; off >>= 1) m = fmaxf(m, __shfl_xor(m, off, 32));
                    float sum = 0.f;
                    for (int w = ln_; w < wnum; w += 32) sum += expf(s_sc[r][n][w] - m);
                    #pragma unroll
                    for (int off = 16; off > 0; off >>= 1) sum += __shfl_xor(sum, off, 32);
                    float inv = 1.f / sum;
                    for (int w = ln_; w < WP_; w += 32)
                        s_sc[r][n][w] = (w < wnum) ? expf(s_sc[r][n][w] - m) * inv : 0.f;
                } else {
                    for (int w = ln_; w < WP_; w += 32) s_sc[r][n][w] = 0.f;
                }
            }
        }
        __syncthreads();

        // ---- ctx = att @ v
        {
            int h = t & 127, half = t >> 7, n = h >> 4;
            const __bf16* vrow = vTb + ((size_t)(li * B_ + b) * H_ + h) * WP_;
            const float4* att0 = (const float4*)(s_sc[0][n]);
            const float4* att1 = (const float4*)(s_sc[1][n]);
            float4 a0 = {0,0,0,0}, a1 = {0,0,0,0};
            #pragma unroll 2
            for (int g = half * 19; g < half * 19 + 19; ++g) {
                bf16x8 vv = *(const bf16x8*)(vrow + 8 * g);
                float4 p00 = att0[2 * g], p01 = att0[2 * g + 1];
                float4 p10 = att1[2 * g], p11 = att1[2 * g + 1];
                float v0 = (float)vv[0], v1 = (float)vv[1], v2 = (float)vv[2], v3 = (float)vv[3];
                float v4 = (float)vv[4], v5 = (float)vv[5], v6 = (float)vv[6], v7 = (float)vv[7];
                a0.x += p00.x * v0 + p01.x * v4;
                a0.y += p00.y * v1 + p01.y * v5;
                a0.z += p00.z * v2 + p01.z * v6;
                a0.w += p00.w * v3 + p01.w * v7;
                a1.x += p10.x * v0 + p11.x * v4;
                a1.y += p10.y * v1 + p11.y * v5;
                a1.z += p10.z * v2 + p11.z * v6;
                a1.w += p10.w * v3 + p11.w * v7;
            }
            s_tmp[0][t] = (a0.x + a0.y) + (a0.z + a0.w);
            s_tmp[1][t] = (a1.x + a1.y) + (a1.z + a1.w);
        }
        __syncthreads();

        // ---- LN1
        if (t < 128) {
            s_red[0][t] = s_tmp[0][t] + s_tmp[0][t + 128] + s_x[0][t];
        } else {
            int e = t - 128;
            s_red[1][e] = s_tmp[1][e] + s_tmp[1][e + 128] + s_x[1][e];
        }
        __syncthreads();
        if (t < 128) {
            int r = t >> 6, l = t & 63;
            float a = s_red[r][l], bb = s_red[r][l + 64];
            float s = a + bb, ss = a * a + bb * bb;
            #pragma unroll
            for (int off = 32; off > 0; off >>= 1) {
                s += __shfl_down(s, off);
                ss += __shfl_down(ss, off);
            }
            if (l == 0) {
                float mean = s * (1.f / 128.f);
                float var = ss * (1.f / 128.f) - mean * mean;
                s_red[r][128] = mean;
                s_red[r][129] = rsqrtf(var + 1e-5f);
            }
        }
        __syncthreads();
        if (t < H_) {
            float g1 = ln1_g[li * H_ + t], b1v = ln1_b[li * H_ + t];
            #pragma unroll
            for (int r = 0; r < 2; ++r)
                s_x[r][t] = (s_red[r][t] - s_red[r][128]) * s_red[r][129] * g1 + b1v;
        }
        __syncthreads();

        // ---- FF hidden
        {
            const __bf16* W1l = W1T + (size_t)li * FF_ * H_;
            int u0 = t * 2;
            const __bf16* ra = W1l + (size_t)u0 * H_;
            const __bf16* rb = W1l + (size_t)(u0 + 1) * H_;
            const float4* x40 = (const float4*)s_x[0];
            const float4* x41 = (const float4*)s_x[1];
            float4 a00 = {0,0,0,0}, a01 = {0,0,0,0}, a10 = {0,0,0,0}, a11 = {0,0,0,0};
            #pragma unroll 2
            for (int g = 0; g < 16; ++g) {
                bf16x8 wa = *(const bf16x8*)(ra + 8 * g);
                bf16x8 wb = *(const bf16x8*)(rb + 8 * g);
                float4 xa0 = x40[2 * g], xa1 = x40[2 * g + 1];
                float4 xb0 = x41[2 * g], xb1 = x41[2 * g + 1];
                a00.x += xa0.x * (float)wa[0] + xa1.x * (float)wa[4];
                a00.y += xa0.y * (float)wa[1] + xa1.y * (float)wa[5];
                a00.z += xa0.z * (float)wa[2] + xa1.z * (float)wa[6];
                a00.w += xa0.w * (float)wa[3] + xa1.w * (float)wa[7];
                a01.x += xa0.x * (float)wb[0] + xa1.x * (float)wb[4];
                a01.y += xa0.y * (float)wb[1] + xa1.y * (float)wb[5];
                a01.z += xa0.z * (float)wb[2] + xa1.z * (float)wb[6];
                a01.w += xa0.w * (float)wb[3] + xa1.w * (float)wb[7];
                a10.x += xb0.x * (float)wa[0] + xb1.x * (float)wa[4];
                a10.y += xb0.y * (float)wa[1] + xb1.y * (float)wa[5];
                a10.z += xb0.z * (float)wa[2] + xb1.z * (float)wa[6];
                a10.w += xb0.w * (float)wa[3] + xb1.w * (float)wa[7];
                a11.x += xb0.x * (float)wb[0] + xb1.x * (float)wb[4];
                a11.y += xb0.y * (float)wb[1] + xb1.y * (float)wb[5];
                a11.z += xb0.z * (float)wb[2] + xb1.z * (float)wb[6];
                a11.w += xb0.w * (float)wb[3] + xb1.w * (float)wb[7];
            }
            float bb0 = b1[li * FF_ + u0], bb1 = b1[li * FF_ + u0 + 1];
            s_hid[0][u0]     = fmaxf((a00.x + a00.y) + (a00.z + a00.w) + bb0, 0.f);
            s_hid[0][u0 + 1] = fmaxf((a01.x + a01.y) + (a01.z + a01.w) + bb1, 0.f);
            s_hid[1][u0]     = fmaxf((a10.x + a10.y) + (a10.z + a10.w) + bb0, 0.f);
            s_hid[1][u0 + 1] = fmaxf((a11.x + a11.y) + (a11.z + a11.w) + bb1, 0.f);
        }
        __syncthreads();

        // ---- FF out
        {
            int half = t >> 7, h = t & 127;
            const __bf16* wrow2 = W2T + ((size_t)li * H_ + h) * FF_ + half * 256;
            const float4* h40 = (const float4*)(s_hid[0] + half * 256);
            const float4* h41 = (const float4*)(s_hid[1] + half * 256);
            float4 a0 = {0,0,0,0}, a1 = {0,0,0,0};
            #pragma unroll 2
            for (int g = 0; g < 32; ++g) {
                bf16x8 wv = *(const bf16x8*)(wrow2 + 8 * g);
                float4 p00 = h40[2 * g], p01 = h40[2 * g + 1];
                float4 p10 = h41[2 * g], p11 = h41[2 * g + 1];
                float v0 = (float)wv[0], v1 = (float)wv[1], v2 = (float)wv[2], v3 = (float)wv[3];
                float v4 = (float)wv[4], v5 = (float)wv[5], v6 = (float)wv[6], v7 = (float)wv[7];
                a0.x += p00.x * v0 + p01.x * v4;
                a0.y += p00.y * v1 + p01.y * v5;
                a0.z += p00.z * v2 + p01.z * v6;
                a0.w += p00.w * v3 + p01.w * v7;
                a1.x += p10.x * v0 + p11.x * v4;
                a1.y += p10.y * v1 + p11.y * v5;
                a1.z += p10.z * v2 + p11.z * v6;
                a1.w += p10.w * v3 + p11.w * v7;
            }
            s_tmp[0][t] = (a0.x + a0.y) + (a0.z + a0.w);
            s_tmp[1][t] = (a1.x + a1.y) + (a1.z + a1.w);
        }
        __syncthreads();

        // ---- LN2
        if (t < 128) {
            s_red[0][t] = s_tmp[0][t] + s_tmp[0][t + 128] + b2[li * H_ + t] + s_x[0][t];
        } else {
            int e = t - 128;
            s_red[1][e] = s_tmp[1][e] + s_tmp[1][e + 128] + b2[li * H_ + e] + s_x[1][e];
        }
        __syncthreads();
        if (t < 128) {
            int r = t >> 6, l = t & 63;
            float a = s_red[r][l], bb = s_red[r][l + 64];
            float s = a + bb, ss = a * a + bb * bb;
            #pragma unroll
            for (int off = 32; off > 0; off >>= 1) {
                s += __shfl_down(s, off);
                ss += __shfl_down(ss, off);
            }
            if (l == 0) {
                float mean = s * (1.f / 128.f);
                float var = ss * (1.f / 128.f) - mean * mean;
                s_red[r][128] = mean;
                s_red[r][129] = rsqrtf(var + 1e-5f);
            }
        }
        __syncthreads();
        if (t < H_) {
            float g2 = ln2_g[li * H_ + t], b2v = ln2_b[li * H_ + t];
            #pragma unroll
            for (int r = 0; r < 2; ++r)
                s_x[r][t] = (s_red[r][t] - s_red[r][128]) * s_red[r][129] * g2 + b2v;
        }
        __syncthreads();
    }

    if (t < H_) {
        out[(b * C_ + c0) * H_ + t] = s_x[0][t];
        out[(b * C_ + c0 + CH_) * H_ + t] = s_x[1][t];
    }
}

extern "C" void kernel_launch(void* const* d_in, const int* in_sizes, int n_in,
                              void* d_out, int out_size, void* d_ws, size_t ws_size,
                              hipStream_t stream) {
    const float* chars  = (const float*)d_in[0];
    const float* words  = (const float*)d_in[1];
    const int* pos_s   = (const int*)d_in[2];
    const int* pos_e   = (const int*)d_in[3];
    const int* lex_s   = (const int*)d_in[4];
    const int* lex_e   = (const int*)d_in[5];
    const int* seq_len = (const int*)d_in[6];
    const int* lex_num = (const int*)d_in[7];
    const float* Wf  = (const float*)d_in[8];
    const float* bfv = (const float*)d_in[9];
    const float* Wq  = (const float*)d_in[10];
    const float* bq  = (const float*)d_in[11];
    const float* Wk  = (const float*)d_in[12];
    const float* bk  = (const float*)d_in[13];
    const float* Wv  = (const float*)d_in[14];
    const float* bv  = (const float*)d_in[15];
    const float* Wr  = (const float*)d_in[16];
    const float* br  = (const float*)d_in[17];
    const float* u_bias = (const float*)d_in[18];
    const float* v_bias = (const float*)d_in[19];
    const float* ln1_g  = (const float*)d_in[20];
    const float* ln1_b  = (const float*)d_in[21];
    const float* ln2_g  = (const float*)d_in[22];
    const float* ln2_b  = (const float*)d_in[23];
    const float* W1  = (const float*)d_in[24];
    const float* b1  = (const float*)d_in[25];
    const float* W2  = (const float*)d_in[26];
    const float* b2  = (const float*)d_in[27];

    __bf16* kb   = (__bf16*)d_ws;                      // L*B*W*H  = 307200 bf16
    __bf16* PEWb = kb + (size_t)L_ * B_ * W_ * H_;     // 262144 bf16
    __bf16* vTb  = PEWb + 4 * PEN_ * H_;               // L*B*H*WP = 311296 bf16
    __bf16* WrB  = vTb + (size_t)L_ * B_ * H_ * WP_;   // 32768 bf16
    __bf16* W1T  = WrB + L_ * H_ * H_;                 // 131072 bf16
    __bf16* W2T  = W1T + L_ * H_ * FF_;                // 131072 bf16

    prep_kernel<<<dim3(PREP_BLOCKS), dim3(128), 0, stream>>>(
        Wf, bfv, words, Wk, bk, Wv, bv, Wr, W1, W2,
        kb, PEWb, vTb, WrB, W1T, W2T);

    mega_kernel<<<dim3(B_ * CH_), dim3(256), 0, stream>>>(
        chars, pos_s, pos_e, lex_s, lex_e, seq_len, lex_num,
        Wq, bq, br, u_bias, v_bias,
        ln1_g, ln1_b, ln2_g, ln2_b, b1, b2,
        kb, PEWb, vTb, WrB, W1T, W2T, (float*)d_out);
}